// Round 8
// baseline (380.606 us; speedup 1.0000x reference)
//
#include <hip/hip_runtime.h>
#include <cstdint>
#include <cstddef>

constexpr int HID = 128;
constexpr int LATENT = 64;
constexpr int BSHIFT = 7;           // 128 nodes per bucket
constexpr int NBUCK_MAX = 512;      // supports up to 65536 nodes
constexpr int EPB = 1024;           // edges per block in bucket passes

typedef __attribute__((ext_vector_type(8))) short short8;
typedef __attribute__((ext_vector_type(4))) float f32x4;

__device__ inline unsigned short f2bf(float f) {
    unsigned u = __float_as_uint(f);
    u += 0x7fff + ((u >> 16) & 1);          // RNE
    return (unsigned short)(u >> 16);
}
__device__ inline unsigned pack_bf16x2(float lo, float hi) {
    unsigned ulo = __float_as_uint(lo);
    unsigned uhi = __float_as_uint(hi);
    ulo += 0x7fff + ((ulo >> 16) & 1);
    uhi += 0x7fff + ((uhi >> 16) & 1);
    return (ulo >> 16) | (uhi & 0xffff0000u);
}

// ---- stage 1 (one launch): bucket partial histograms + WT conv + x->bf16 conv ----
__global__ __launch_bounds__(256) void stage1_k(const int* __restrict__ dst,
                                                const float* __restrict__ x,
                                                const float* __restrict__ Wl,
                                                const float* __restrict__ Wr,
                                                int* __restrict__ partial,
                                                unsigned* __restrict__ hx2,
                                                unsigned short* __restrict__ WT,
                                                int* __restrict__ row_ptr,
                                                int nE, int nbuck, int ebB, int n2x, int nN) {
    if (blockIdx.x < (unsigned)ebB) {
        if (blockIdx.x == 0 && threadIdx.x == 0) row_ptr[nN] = nE;
        __shared__ int lh[NBUCK_MAX];
        for (int b = threadIdx.x; b < nbuck; b += 256) lh[b] = 0;
        __syncthreads();
        int base = blockIdx.x * EPB;
        int end = min(base + EPB, nE);
        for (int i = base + threadIdx.x; i < end; i += 256)
            atomicAdd(&lh[dst[i] >> BSHIFT], 1);
        __syncthreads();
        int* row = partial + (size_t)blockIdx.x * NBUCK_MAX;
        for (int b = threadIdx.x; b < nbuck; b += 256) row[b] = lh[b];
    } else if (blockIdx.x < (unsigned)(ebB + 384)) {
        int idx = (blockIdx.x - ebB) * 256 + threadIdx.x;    // < 3*128*256
        int l = idx / (128 * 256);
        int rem = idx % (128 * 256);
        int n = rem / 256;
        int k = rem % 256;
        float v = (k < 128) ? Wl[(size_t)l * 16384 + (size_t)k * 128 + n]
                            : Wr[(size_t)l * 16384 + (size_t)(k - 128) * 128 + n];
        WT[idx] = f2bf(v);
    } else {
        int i = (blockIdx.x - ebB - 384) * 256 + threadIdx.x;
        if (i < n2x) {
            float2 v = ((const float2*)x)[i];
            hx2[i] = pack_bf16x2(v.x, v.y);
        }
    }
}

// ---- stage 2: per-bucket column scan over block partials (one block per bucket) ----
__global__ __launch_bounds__(256) void colscan_k(int* __restrict__ partial,
                                                 int* __restrict__ bucketTotal, int ebB) {
    int b = blockIdx.x;
    int t = threadIdx.x;
    const int CH = (ebB + 255) / 256;     // <= 8 for ebB <= 2048
    int vals[8];
    int s = 0;
    #pragma unroll
    for (int c = 0; c < 8; ++c) {
        if (c >= CH) break;
        int k = t * CH + c;
        int v = (k < ebB) ? partial[(size_t)k * NBUCK_MAX + b] : 0;
        vals[c] = v; s += v;
    }
    __shared__ int part[256];
    part[t] = s;
    __syncthreads();
    for (int d = 1; d < 256; d <<= 1) {
        int u = (t >= d) ? part[t - d] : 0;
        __syncthreads();
        if (t >= d) part[t] += u;
        __syncthreads();
    }
    int run = (t == 0) ? 0 : part[t - 1];
    #pragma unroll
    for (int c = 0; c < 8; ++c) {
        if (c >= CH) break;
        int k = t * CH + c;
        if (k < ebB) partial[(size_t)k * NBUCK_MAX + b] = run;
        run += vals[c];
    }
    if (t == 255) bucketTotal[b] = run;
}

// ---- stage 3: bucket placement; bucketStart recomputed locally from bucketTotal ----
__global__ __launch_bounds__(256) void bplace_k(const int* __restrict__ src,
                                                const int* __restrict__ dst,
                                                const int* __restrict__ partial,
                                                const int* __restrict__ bucketTotal,
                                                uint2* __restrict__ staged, int nE, int nbuck) {
    __shared__ int lh[NBUCK_MAX];
    __shared__ int lb[NBUCK_MAX];
    __shared__ int part[256];
    int t = threadIdx.x;
    for (int b = t; b < nbuck; b += 256) lh[b] = 0;
    int v0 = (2 * t < nbuck) ? bucketTotal[2 * t] : 0;
    int v1 = (2 * t + 1 < nbuck) ? bucketTotal[2 * t + 1] : 0;
    part[t] = v0 + v1;
    __syncthreads();
    for (int d = 1; d < 256; d <<= 1) {
        int u = (t >= d) ? part[t - d] : 0;
        __syncthreads();
        if (t >= d) part[t] += u;
        __syncthreads();
    }
    const int* myPre = partial + (size_t)blockIdx.x * NBUCK_MAX;
    int excl = part[t] - v0 - v1;       // exclusive prefix of pair t
    if (2 * t < nbuck)     lb[2 * t]     = excl + myPre[2 * t];
    if (2 * t + 1 < nbuck) lb[2 * t + 1] = excl + v0 + myPre[2 * t + 1];
    __syncthreads();
    int base = blockIdx.x * EPB;
    int end = min(base + EPB, nE);
    for (int i = base + t; i < end; i += 256) {
        int d = dst[i];
        int b = d >> BSHIFT;
        int loc = atomicAdd(&lh[b], 1);      // LDS-only cursor
        staged[lb[b] + loc] = make_uint2((unsigned)src[i], (unsigned)d);
    }
}

// ---- stage 4: per-bucket finish: counts -> row_ptr/inv, place csr_src (L2-local) ----
__global__ __launch_bounds__(256) void sort_bucket_k(const uint2* __restrict__ staged,
                                                     const int* __restrict__ bucketTotal,
                                                     int* __restrict__ row_ptr,
                                                     float* __restrict__ inv,
                                                     int* __restrict__ csr_src, int nN, int nbuck) {
    __shared__ int part[256];
    __shared__ int cnt[128];
    __shared__ int rp[128];
    __shared__ int sBeg;
    int g = blockIdx.x;
    int t = threadIdx.x;
    int v0 = (2 * t < nbuck) ? bucketTotal[2 * t] : 0;
    int v1 = (2 * t + 1 < nbuck) ? bucketTotal[2 * t + 1] : 0;
    part[t] = v0 + v1;
    __syncthreads();
    for (int d = 1; d < 256; d <<= 1) {
        int u = (t >= d) ? part[t - d] : 0;
        __syncthreads();
        if (t >= d) part[t] += u;
        __syncthreads();
    }
    if (t == (g >> 1)) {
        int excl = part[t] - v0 - v1;
        sBeg = (g & 1) ? (excl + v0) : excl;
    }
    if (t < 128) cnt[t] = 0;
    __syncthreads();
    int beg = sBeg;
    int end = beg + bucketTotal[g];
    for (int i = beg + t; i < end; i += 256)
        atomicAdd(&cnt[staged[i].y & 127], 1);
    __syncthreads();
    if (t < 128) rp[t] = cnt[t];
    __syncthreads();
    #pragma unroll
    for (int d = 1; d < 128; d <<= 1) {
        int v = 0;
        if (t < 128 && t >= d) v = rp[t - d];
        __syncthreads();
        if (t < 128 && t >= d) rp[t] += v;
        __syncthreads();
    }
    if (t < 128) {
        int c = cnt[t];
        int excl = rp[t] - c;
        int node = (g << BSHIFT) + t;
        if (node < nN) {
            row_ptr[node] = beg + excl;
            inv[node] = 1.0f / fmaxf((float)c, 1.0f);
        }
        cnt[t] = excl;               // reuse as cursor
    }
    __syncthreads();
    for (int i = beg + t; i < end; i += 256) {
        uint2 e = staged[i];
        int pos = atomicAdd(&cnt[e.y & 127], 1);
        csr_src[beg + pos] = (int)e.x;
    }
}

// ---------------- pull-gather mean: uint4 loads, 16 lanes/row, 4-deep ILP ----------------
// 256 thr = 4 waves, ONE NODE PER WAVE (round-2 A/B: serializing nodes per wave costs ~2x).
// Round-7: predicated loads (verified, -9us/layer). Round-8: NPASS=4 src-range passes --
// each pass touches a 3.2MB h-range that fits every XCD's 4MB L2, converting the 2x/XCD
// reuse from LLC-serviced to L2-serviced. Edge-index re-scan x4 is L1/L2-hot (cheap).
__global__ __launch_bounds__(256) void gather_k(const int* __restrict__ row_ptr,
                                                const int* __restrict__ csr_src,
                                                const float* __restrict__ inv,
                                                const uint4* __restrict__ h4,
                                                uint4* __restrict__ mean4, int nN) {
    int w = blockIdx.x * 4 + (threadIdx.x >> 6);
    if (w >= nN) return;
    int lane = threadIdx.x & 63;
    int quarter = lane >> 4;
    int col = lane & 15;
    int beg = row_ptr[w], end = row_ptr[w + 1];
    float accA[8] = {}, accB[8] = {}, accC[8] = {}, accD[8] = {};
    const int NPASS = 4;
    const int rsz = (nN + NPASS - 1) / NPASS;
    for (int r = 0; r < NPASS; ++r) {
        int rlo = r * rsz;
        int rhi = rlo + rsz;                 // exclusive; last pass covers remainder (s < nN < rhi)
        for (int base = beg; base < end; base += 64) {
            int navail = min(64, end - base);
            int idx = (lane < navail) ? csr_src[base + lane] : 0;
            for (int j = 0; j < navail; j += 16) {
                int e0 = j + quarter;
                int e1 = j + 4 + quarter;
                int e2 = j + 8 + quarter;
                int e3 = j + 12 + quarter;
                int s0 = __shfl(idx, e0, 64);
                int s1 = __shfl(idx, e1, 64);
                int s2 = __shfl(idx, e2, 64);
                int s3 = __shfl(idx, e3, 64);
                bool p0 = (e0 < navail) && (s0 >= rlo) && (s0 < rhi);
                bool p1 = (e1 < navail) && (s1 >= rlo) && (s1 < rhi);
                bool p2 = (e2 < navail) && (s2 >= rlo) && (s2 < rhi);
                bool p3 = (e3 < navail) && (s3 >= rlo) && (s3 < rhi);
                if (p0) {
                    uint4 u0 = h4[(size_t)s0 * 16 + col];
                    accA[0] += __uint_as_float(u0.x << 16); accA[1] += __uint_as_float(u0.x & 0xffff0000u);
                    accA[2] += __uint_as_float(u0.y << 16); accA[3] += __uint_as_float(u0.y & 0xffff0000u);
                    accA[4] += __uint_as_float(u0.z << 16); accA[5] += __uint_as_float(u0.z & 0xffff0000u);
                    accA[6] += __uint_as_float(u0.w << 16); accA[7] += __uint_as_float(u0.w & 0xffff0000u);
                }
                if (p1) {
                    uint4 u1 = h4[(size_t)s1 * 16 + col];
                    accB[0] += __uint_as_float(u1.x << 16); accB[1] += __uint_as_float(u1.x & 0xffff0000u);
                    accB[2] += __uint_as_float(u1.y << 16); accB[3] += __uint_as_float(u1.y & 0xffff0000u);
                    accB[4] += __uint_as_float(u1.z << 16); accB[5] += __uint_as_float(u1.z & 0xffff0000u);
                    accB[6] += __uint_as_float(u1.w << 16); accB[7] += __uint_as_float(u1.w & 0xffff0000u);
                }
                if (p2) {
                    uint4 u2 = h4[(size_t)s2 * 16 + col];
                    accC[0] += __uint_as_float(u2.x << 16); accC[1] += __uint_as_float(u2.x & 0xffff0000u);
                    accC[2] += __uint_as_float(u2.y << 16); accC[3] += __uint_as_float(u2.y & 0xffff0000u);
                    accC[4] += __uint_as_float(u2.z << 16); accC[5] += __uint_as_float(u2.z & 0xffff0000u);
                    accC[6] += __uint_as_float(u2.w << 16); accC[7] += __uint_as_float(u2.w & 0xffff0000u);
                }
                if (p3) {
                    uint4 u3 = h4[(size_t)s3 * 16 + col];
                    accD[0] += __uint_as_float(u3.x << 16); accD[1] += __uint_as_float(u3.x & 0xffff0000u);
                    accD[2] += __uint_as_float(u3.y << 16); accD[3] += __uint_as_float(u3.y & 0xffff0000u);
                    accD[4] += __uint_as_float(u3.z << 16); accD[5] += __uint_as_float(u3.z & 0xffff0000u);
                    accD[6] += __uint_as_float(u3.w << 16); accD[7] += __uint_as_float(u3.w & 0xffff0000u);
                }
            }
        }
    }
    #pragma unroll
    for (int k = 0; k < 8; ++k) {
        float v = (accA[k] + accB[k]) + (accC[k] + accD[k]);
        v += __shfl_xor(v, 16, 64);
        v += __shfl_xor(v, 32, 64);
        accA[k] = v;
    }
    if (quarter == 0) {
        float iv = inv[w];
        uint4 o;
        o.x = pack_bf16x2(accA[0] * iv, accA[1] * iv);
        o.y = pack_bf16x2(accA[2] * iv, accA[3] * iv);
        o.z = pack_bf16x2(accA[4] * iv, accA[5] * iv);
        o.w = pack_bf16x2(accA[6] * iv, accA[7] * iv);
        mean4[(size_t)w * 16 + col] = o;
    }
}

// ---------------- MFMA SAGE transform: out = relu([mean|h] @ WT^T + bl), bf16 ----------------
// 512 thr / 128 rows per block (verified round 5): 64KB LDS WT stage serves 2x rows;
// WT staging traffic halved vs 256-thr version. L2-direct B-read is ~2x slower (round-4 A/B).
__global__ __launch_bounds__(512) void sage_mfma_k(
    const unsigned short* __restrict__ mean,
    const unsigned short* __restrict__ h,
    const unsigned short* __restrict__ WT,   // [128][256] bf16
    const float* __restrict__ bl,
    unsigned short* __restrict__ out, int nN)
{
    __shared__ unsigned short sB[128 * 256];   // exactly 64 KB

    {
        int row = threadIdx.x >> 2, seg = threadIdx.x & 3;
        const short8* srcp = (const short8*)(WT + row * 256 + seg * 64);
        int sw = (row & 7) << 2;
        #pragma unroll
        for (int j = 0; j < 8; ++j) {
            int unit = seg * 8 + j;
            int unit2 = unit ^ sw;
            *(short8*)(sB + row * 256 + unit2 * 8) = srcp[j];
        }
    }
    __syncthreads();

    const int wave = threadIdx.x >> 6;       // 0..7
    const int lane = threadIdx.x & 63;
    const int m = lane & 15;
    const int q = lane >> 4;
    const int row = blockIdx.x * 128 + wave * 16 + m;
    const int rowc = min(row, nN - 1);
    const int swm = (m & 7) << 2;

    f32x4 acc[8] = {};
    #pragma unroll
    for (int ks = 0; ks < 8; ++ks) {
        const unsigned short* Aptr = (ks < 4) ? mean : h;
        short8 a = *(const short8*)(Aptr + (size_t)rowc * HID + (ks & 3) * 32 + q * 8);
        #pragma unroll
        for (int t = 0; t < 8; ++t) {
            int unit2 = (ks * 4 + q) ^ swm;
            short8 b = *(const short8*)(sB + (t * 16 + m) * 256 + unit2 * 8);
            acc[t] = __builtin_amdgcn_mfma_f32_16x16x32_bf16(a, b, acc[t], 0, 0, 0);
        }
    }

    int orow_base = blockIdx.x * 128 + wave * 16 + q * 4;
    #pragma unroll
    for (int t = 0; t < 8; ++t) {
        float bias = bl[t * 16 + m];
        #pragma unroll
        for (int r = 0; r < 4; ++r) {
            int orow = orow_base + r;
            if (orow < nN) {
                float v = fmaxf(acc[t][r] + bias, 0.f);
                out[(size_t)orow * HID + t * 16 + m] = f2bf(v);
            }
        }
    }
}

// ---------------- segmented pool (batch sorted): one block per graph ----------------
__global__ __launch_bounds__(256) void pool_seg_k(const unsigned* __restrict__ h2,
                                                  const int* __restrict__ batch,
                                                  float* __restrict__ pooled, int nN) {
    int g = blockIdx.x;
    int lo = 0, hi = nN;
    while (lo < hi) { int mid = (lo + hi) >> 1; if (batch[mid] < g) lo = mid + 1; else hi = mid; }
    int beg = lo;
    hi = nN;
    while (lo < hi) { int mid = (lo + hi) >> 1; if (batch[mid] <= g) lo = mid + 1; else hi = mid; }
    int end = lo;

    int lane = threadIdx.x & 63;
    int sub  = threadIdx.x >> 6;          // 4 waves
    float s0 = 0.f, s1 = 0.f;
    for (int i = beg + sub; i < end; i += 4) {
        unsigned u = h2[(size_t)i * 64 + lane];
        s0 += __uint_as_float(u << 16);
        s1 += __uint_as_float(u & 0xffff0000u);
    }
    __shared__ float red[4][HID];
    red[sub][2 * lane]     = s0;
    red[sub][2 * lane + 1] = s1;
    __syncthreads();
    if (sub == 0) {
        float v0 = red[0][2 * lane] + red[1][2 * lane] + red[2][2 * lane] + red[3][2 * lane];
        float v1 = red[0][2 * lane + 1] + red[1][2 * lane + 1] + red[2][2 * lane + 1] + red[3][2 * lane + 1];
        pooled[(size_t)g * HID + 2 * lane]     = v0;
        pooled[(size_t)g * HID + 2 * lane + 1] = v1;
    }
}

// ---------------- batchnorm stats: 1024 thr, 8 graph-stripes x 128 features ----------------
__global__ __launch_bounds__(1024) void bn_stats_k(const float* __restrict__ pooled,
                                                   const float* __restrict__ gamma,
                                                   const float* __restrict__ beta,
                                                   float* __restrict__ scale,
                                                   float* __restrict__ shift, int nG) {
    __shared__ float rs[8][HID], rs2[8][HID];
    int j = threadIdx.x & (HID - 1);
    int stripe = threadIdx.x >> 7;         // 0..7
    float s = 0.f, s2 = 0.f;
    for (int g = stripe; g < nG; g += 8) {
        float v = pooled[(size_t)g * HID + j];
        s += v; s2 += v * v;
    }
    rs[stripe][j] = s; rs2[stripe][j] = s2;
    __syncthreads();
    if (threadIdx.x < HID) {
        float S = 0.f, S2 = 0.f;
        #pragma unroll
        for (int k = 0; k < 8; ++k) { S += rs[k][j]; S2 += rs2[k][j]; }
        float invG = 1.0f / (float)nG;
        float mu = S * invG;
        float var = S2 * invG - mu * mu;
        float r = rsqrtf(var + 1e-5f) * gamma[j];
        scale[j] = r;
        shift[j] = beta[j] - mu * r;
    }
}

// ---------------- final FC: one block per graph (round-3 lesson: never collapse to 1 block) ----------------
__global__ __launch_bounds__(LATENT) void fc_k(const float* __restrict__ pooled,
                                               const float* __restrict__ scale,
                                               const float* __restrict__ shift,
                                               const float* __restrict__ fcW,
                                               const float* __restrict__ fcb,
                                               float* __restrict__ out, int nG) {
    int g = blockIdx.x;
    int o = threadIdx.x;
    float acc = fcb[o];
    for (int j = 0; j < HID; ++j) {
        float v = pooled[(size_t)g * HID + j] * scale[j] + shift[j];
        acc += v * fcW[(size_t)j * LATENT + o];
    }
    out[(size_t)g * LATENT + o] = acc;
}

extern "C" void kernel_launch(void* const* d_in, const int* in_sizes, int n_in,
                              void* d_out, int out_size, void* d_ws, size_t ws_size,
                              hipStream_t stream) {
    const float* x     = (const float*)d_in[0];
    const int*   ei    = (const int*)d_in[1];
    const int*   batch = (const int*)d_in[2];
    const float* Wl    = (const float*)d_in[3];
    const float* bl    = (const float*)d_in[4];
    const float* Wr    = (const float*)d_in[5];
    const float* gamma = (const float*)d_in[6];
    const float* beta  = (const float*)d_in[7];
    const float* fcW   = (const float*)d_in[8];
    const float* fcb   = (const float*)d_in[9];
    float* out = (float*)d_out;

    const int nN = in_sizes[0] / HID;      // 50000
    const int nE = in_sizes[1] / 2;        // 800000
    const int nG = out_size / LATENT;      // 256
    const int* src = ei;
    const int* dst = ei + nE;
    const int nbuck = (nN + 127) >> BSHIFT;   // 391
    const int ebB = (nE + EPB - 1) / EPB;     // 782

    unsigned short* hx   = (unsigned short*)d_ws;           // nN*HID bf16
    unsigned short* B1   = hx + (size_t)nN * HID;
    unsigned short* B2   = B1 + (size_t)nN * HID;
    unsigned short* mean = B2 + (size_t)nN * HID;           // aliased by staged (CSR phase only)
    unsigned short* WT   = mean + (size_t)nN * HID;         // 3*128*256 bf16
    float* inv    = (float*)(WT + 3 * 128 * 256);
    float* pooled = inv + nN;
    float* scale  = pooled + (size_t)nG * HID;
    float* shift  = scale + HID;
    int*   row_ptr     = (int*)(shift + HID);               // nN+1
    int*   csr_src     = row_ptr + (nN + 1);
    int*   bucketStart = csr_src + nE;                      // (layout kept)
    int*   bucketTotal = bucketStart + NBUCK_MAX + 1;
    int*   partial     = bucketTotal + NBUCK_MAX;           // ebB*NBUCK_MAX ints
    uint2* staged      = (uint2*)mean;                      // 6.4 MB <= mean's 12.8 MB

    const int n2x = nN * HID / 2;
    const int convx_blocks = (n2x + 255) / 256;

    // ---- CSR build + conversions: 4 launches (coop grid.sync measured ~100us/sync - banned) ----
    stage1_k<<<ebB + 384 + convx_blocks, 256, 0, stream>>>(dst, x, Wl, Wr, partial,
                                                           (unsigned*)hx, WT, row_ptr,
                                                           nE, nbuck, ebB, n2x, nN);
    colscan_k<<<nbuck, 256, 0, stream>>>(partial, bucketTotal, ebB);
    bplace_k<<<ebB, 256, 0, stream>>>(src, dst, partial, bucketTotal, staged, nE, nbuck);
    sort_bucket_k<<<nbuck, 256, 0, stream>>>(staged, bucketTotal, row_ptr, inv, csr_src, nN, nbuck);

    const int gather_blocks = (nN + 3) / 4;
    const int gemm_blocks = (nN + 127) / 128;

    const unsigned short* hcur = hx;
    unsigned short* outs[3] = {B1, B2, B1};
    for (int l = 0; l < 3; ++l) {
        gather_k<<<gather_blocks, 256, 0, stream>>>(row_ptr, csr_src, inv,
                                                    (const uint4*)hcur, (uint4*)mean, nN);
        sage_mfma_k<<<gemm_blocks, 512, 0, stream>>>(mean, hcur,
                                                     WT + (size_t)l * 128 * 256,
                                                     bl + (size_t)l * HID,
                                                     outs[l], nN);
        hcur = outs[l];
    }

    pool_seg_k<<<nG, 256, 0, stream>>>((const unsigned*)hcur, batch, pooled, nN);
    bn_stats_k<<<1, 1024, 0, stream>>>(pooled, gamma, beta, scale, shift, nG);
    fc_k<<<nG, LATENT, 0, stream>>>(pooled, scale, shift, fcW, fcb, out, nG);
}

// Round 9
// 284.875 us; speedup vs baseline: 1.3360x; 1.3360x over previous
//
#include <hip/hip_runtime.h>
#include <cstdint>
#include <cstddef>

constexpr int HID = 128;
constexpr int LATENT = 64;
constexpr int BSHIFT = 7;           // 128 nodes per bucket
constexpr int NBUCK_MAX = 512;      // supports up to 65536 nodes
constexpr int EPB = 1024;           // edges per block in bucket passes

typedef __attribute__((ext_vector_type(8))) short short8;
typedef __attribute__((ext_vector_type(4))) float f32x4;

__device__ inline unsigned short f2bf(float f) {
    unsigned u = __float_as_uint(f);
    u += 0x7fff + ((u >> 16) & 1);          // RNE
    return (unsigned short)(u >> 16);
}
__device__ inline unsigned pack_bf16x2(float lo, float hi) {
    unsigned ulo = __float_as_uint(lo);
    unsigned uhi = __float_as_uint(hi);
    ulo += 0x7fff + ((ulo >> 16) & 1);
    uhi += 0x7fff + ((uhi >> 16) & 1);
    return (ulo >> 16) | (uhi & 0xffff0000u);
}

// ---- stage 1 (one launch): bucket partial histograms + WT conv + x->bf16 conv ----
__global__ __launch_bounds__(256) void stage1_k(const int* __restrict__ dst,
                                                const float* __restrict__ x,
                                                const float* __restrict__ Wl,
                                                const float* __restrict__ Wr,
                                                int* __restrict__ partial,
                                                unsigned* __restrict__ hx2,
                                                unsigned short* __restrict__ WT,
                                                int* __restrict__ row_ptr,
                                                int nE, int nbuck, int ebB, int n2x, int nN) {
    if (blockIdx.x < (unsigned)ebB) {
        if (blockIdx.x == 0 && threadIdx.x == 0) row_ptr[nN] = nE;
        __shared__ int lh[NBUCK_MAX];
        for (int b = threadIdx.x; b < nbuck; b += 256) lh[b] = 0;
        __syncthreads();
        int base = blockIdx.x * EPB;
        int end = min(base + EPB, nE);
        for (int i = base + threadIdx.x; i < end; i += 256)
            atomicAdd(&lh[dst[i] >> BSHIFT], 1);
        __syncthreads();
        int* row = partial + (size_t)blockIdx.x * NBUCK_MAX;
        for (int b = threadIdx.x; b < nbuck; b += 256) row[b] = lh[b];
    } else if (blockIdx.x < (unsigned)(ebB + 384)) {
        int idx = (blockIdx.x - ebB) * 256 + threadIdx.x;    // < 3*128*256
        int l = idx / (128 * 256);
        int rem = idx % (128 * 256);
        int n = rem / 256;
        int k = rem % 256;
        float v = (k < 128) ? Wl[(size_t)l * 16384 + (size_t)k * 128 + n]
                            : Wr[(size_t)l * 16384 + (size_t)(k - 128) * 128 + n];
        WT[idx] = f2bf(v);
    } else {
        int i = (blockIdx.x - ebB - 384) * 256 + threadIdx.x;
        if (i < n2x) {
            float2 v = ((const float2*)x)[i];
            hx2[i] = pack_bf16x2(v.x, v.y);
        }
    }
}

// ---- stage 2: per-bucket column scan over block partials (one block per bucket) ----
__global__ __launch_bounds__(256) void colscan_k(int* __restrict__ partial,
                                                 int* __restrict__ bucketTotal, int ebB) {
    int b = blockIdx.x;
    int t = threadIdx.x;
    const int CH = (ebB + 255) / 256;     // <= 8 for ebB <= 2048
    int vals[8];
    int s = 0;
    #pragma unroll
    for (int c = 0; c < 8; ++c) {
        if (c >= CH) break;
        int k = t * CH + c;
        int v = (k < ebB) ? partial[(size_t)k * NBUCK_MAX + b] : 0;
        vals[c] = v; s += v;
    }
    __shared__ int part[256];
    part[t] = s;
    __syncthreads();
    for (int d = 1; d < 256; d <<= 1) {
        int u = (t >= d) ? part[t - d] : 0;
        __syncthreads();
        if (t >= d) part[t] += u;
        __syncthreads();
    }
    int run = (t == 0) ? 0 : part[t - 1];
    #pragma unroll
    for (int c = 0; c < 8; ++c) {
        if (c >= CH) break;
        int k = t * CH + c;
        if (k < ebB) partial[(size_t)k * NBUCK_MAX + b] = run;
        run += vals[c];
    }
    if (t == 255) bucketTotal[b] = run;
}

// ---- stage 3: bucket placement; bucketStart recomputed locally from bucketTotal ----
__global__ __launch_bounds__(256) void bplace_k(const int* __restrict__ src,
                                                const int* __restrict__ dst,
                                                const int* __restrict__ partial,
                                                const int* __restrict__ bucketTotal,
                                                uint2* __restrict__ staged, int nE, int nbuck) {
    __shared__ int lh[NBUCK_MAX];
    __shared__ int lb[NBUCK_MAX];
    __shared__ int part[256];
    int t = threadIdx.x;
    for (int b = t; b < nbuck; b += 256) lh[b] = 0;
    int v0 = (2 * t < nbuck) ? bucketTotal[2 * t] : 0;
    int v1 = (2 * t + 1 < nbuck) ? bucketTotal[2 * t + 1] : 0;
    part[t] = v0 + v1;
    __syncthreads();
    for (int d = 1; d < 256; d <<= 1) {
        int u = (t >= d) ? part[t - d] : 0;
        __syncthreads();
        if (t >= d) part[t] += u;
        __syncthreads();
    }
    const int* myPre = partial + (size_t)blockIdx.x * NBUCK_MAX;
    int excl = part[t] - v0 - v1;       // exclusive prefix of pair t
    if (2 * t < nbuck)     lb[2 * t]     = excl + myPre[2 * t];
    if (2 * t + 1 < nbuck) lb[2 * t + 1] = excl + v0 + myPre[2 * t + 1];
    __syncthreads();
    int base = blockIdx.x * EPB;
    int end = min(base + EPB, nE);
    for (int i = base + t; i < end; i += 256) {
        int d = dst[i];
        int b = d >> BSHIFT;
        int loc = atomicAdd(&lh[b], 1);      // LDS-only cursor
        staged[lb[b] + loc] = make_uint2((unsigned)src[i], (unsigned)d);
    }
}

// ---- stage 4: per-bucket finish: counts -> row_ptr/inv, place csr_src (L2-local) ----
__global__ __launch_bounds__(256) void sort_bucket_k(const uint2* __restrict__ staged,
                                                     const int* __restrict__ bucketTotal,
                                                     int* __restrict__ row_ptr,
                                                     float* __restrict__ inv,
                                                     int* __restrict__ csr_src, int nN, int nbuck) {
    __shared__ int part[256];
    __shared__ int cnt[128];
    __shared__ int rp[128];
    __shared__ int sBeg;
    int g = blockIdx.x;
    int t = threadIdx.x;
    int v0 = (2 * t < nbuck) ? bucketTotal[2 * t] : 0;
    int v1 = (2 * t + 1 < nbuck) ? bucketTotal[2 * t + 1] : 0;
    part[t] = v0 + v1;
    __syncthreads();
    for (int d = 1; d < 256; d <<= 1) {
        int u = (t >= d) ? part[t - d] : 0;
        __syncthreads();
        if (t >= d) part[t] += u;
        __syncthreads();
    }
    if (t == (g >> 1)) {
        int excl = part[t] - v0 - v1;
        sBeg = (g & 1) ? (excl + v0) : excl;
    }
    if (t < 128) cnt[t] = 0;
    __syncthreads();
    int beg = sBeg;
    int end = beg + bucketTotal[g];
    for (int i = beg + t; i < end; i += 256)
        atomicAdd(&cnt[staged[i].y & 127], 1);
    __syncthreads();
    if (t < 128) rp[t] = cnt[t];
    __syncthreads();
    #pragma unroll
    for (int d = 1; d < 128; d <<= 1) {
        int v = 0;
        if (t < 128 && t >= d) v = rp[t - d];
        __syncthreads();
        if (t < 128 && t >= d) rp[t] += v;
        __syncthreads();
    }
    if (t < 128) {
        int c = cnt[t];
        int excl = rp[t] - c;
        int node = (g << BSHIFT) + t;
        if (node < nN) {
            row_ptr[node] = beg + excl;
            inv[node] = 1.0f / fmaxf((float)c, 1.0f);
        }
        cnt[t] = excl;               // reuse as cursor
    }
    __syncthreads();
    for (int i = beg + t; i < end; i += 256) {
        uint2 e = staged[i];
        int pos = atomicAdd(&cnt[e.y & 127], 1);
        csr_src[beg + pos] = (int)e.x;
    }
}

// ---------------- pull-gather mean: uint4 loads, 16 lanes/row, 4-deep ILP ----------------
// 256 thr = 4 waves, ONE NODE PER WAVE. ROUND-7 VERIFIED VERSION (288.6us).
// Round-8 A/B: NPASS src-range passes regress 1.8x (VALU issue-bound, 53% VALUBusy) --
// gather runs at ~6.0 TB/s = 256CU x 10B/cy/CU, the per-CU VMEM service-rate ceiling.
// Locality transforms cannot beat a service-rate limit. This kernel is CLOSED.
__global__ __launch_bounds__(256) void gather_k(const int* __restrict__ row_ptr,
                                                const int* __restrict__ csr_src,
                                                const float* __restrict__ inv,
                                                const uint4* __restrict__ h4,
                                                uint4* __restrict__ mean4, int nN) {
    int w = blockIdx.x * 4 + (threadIdx.x >> 6);
    if (w >= nN) return;
    int lane = threadIdx.x & 63;
    int quarter = lane >> 4;
    int col = lane & 15;
    int beg = row_ptr[w], end = row_ptr[w + 1];
    float accA[8] = {}, accB[8] = {}, accC[8] = {}, accD[8] = {};
    for (int base = beg; base < end; base += 64) {
        int navail = min(64, end - base);
        int idx = (lane < navail) ? csr_src[base + lane] : 0;
        for (int j = 0; j < navail; j += 16) {
            int e0 = j + quarter;
            int e1 = j + 4 + quarter;
            int e2 = j + 8 + quarter;
            int e3 = j + 12 + quarter;
            int s0 = __shfl(idx, e0, 64);     // e* < 64 always; invalid slots read idx=0 (unused)
            int s1 = __shfl(idx, e1, 64);
            int s2 = __shfl(idx, e2, 64);
            int s3 = __shfl(idx, e3, 64);
            uint4 u0 = make_uint4(0u, 0u, 0u, 0u);
            uint4 u1 = make_uint4(0u, 0u, 0u, 0u);
            uint4 u2 = make_uint4(0u, 0u, 0u, 0u);
            uint4 u3 = make_uint4(0u, 0u, 0u, 0u);
            if (e0 < navail) u0 = h4[(size_t)s0 * 16 + col];
            if (e1 < navail) u1 = h4[(size_t)s1 * 16 + col];
            if (e2 < navail) u2 = h4[(size_t)s2 * 16 + col];
            if (e3 < navail) u3 = h4[(size_t)s3 * 16 + col];
            if (e0 < navail) {
                accA[0] += __uint_as_float(u0.x << 16); accA[1] += __uint_as_float(u0.x & 0xffff0000u);
                accA[2] += __uint_as_float(u0.y << 16); accA[3] += __uint_as_float(u0.y & 0xffff0000u);
                accA[4] += __uint_as_float(u0.z << 16); accA[5] += __uint_as_float(u0.z & 0xffff0000u);
                accA[6] += __uint_as_float(u0.w << 16); accA[7] += __uint_as_float(u0.w & 0xffff0000u);
            }
            if (e1 < navail) {
                accB[0] += __uint_as_float(u1.x << 16); accB[1] += __uint_as_float(u1.x & 0xffff0000u);
                accB[2] += __uint_as_float(u1.y << 16); accB[3] += __uint_as_float(u1.y & 0xffff0000u);
                accB[4] += __uint_as_float(u1.z << 16); accB[5] += __uint_as_float(u1.z & 0xffff0000u);
                accB[6] += __uint_as_float(u1.w << 16); accB[7] += __uint_as_float(u1.w & 0xffff0000u);
            }
            if (e2 < navail) {
                accC[0] += __uint_as_float(u2.x << 16); accC[1] += __uint_as_float(u2.x & 0xffff0000u);
                accC[2] += __uint_as_float(u2.y << 16); accC[3] += __uint_as_float(u2.y & 0xffff0000u);
                accC[4] += __uint_as_float(u2.z << 16); accC[5] += __uint_as_float(u2.z & 0xffff0000u);
                accC[6] += __uint_as_float(u2.w << 16); accC[7] += __uint_as_float(u2.w & 0xffff0000u);
            }
            if (e3 < navail) {
                accD[0] += __uint_as_float(u3.x << 16); accD[1] += __uint_as_float(u3.x & 0xffff0000u);
                accD[2] += __uint_as_float(u3.y << 16); accD[3] += __uint_as_float(u3.y & 0xffff0000u);
                accD[4] += __uint_as_float(u3.z << 16); accD[5] += __uint_as_float(u3.z & 0xffff0000u);
                accD[6] += __uint_as_float(u3.w << 16); accD[7] += __uint_as_float(u3.w & 0xffff0000u);
            }
        }
    }
    #pragma unroll
    for (int k = 0; k < 8; ++k) {
        float v = (accA[k] + accB[k]) + (accC[k] + accD[k]);
        v += __shfl_xor(v, 16, 64);
        v += __shfl_xor(v, 32, 64);
        accA[k] = v;
    }
    if (quarter == 0) {
        float iv = inv[w];
        uint4 o;
        o.x = pack_bf16x2(accA[0] * iv, accA[1] * iv);
        o.y = pack_bf16x2(accA[2] * iv, accA[3] * iv);
        o.z = pack_bf16x2(accA[4] * iv, accA[5] * iv);
        o.w = pack_bf16x2(accA[6] * iv, accA[7] * iv);
        mean4[(size_t)w * 16 + col] = o;
    }
}

// ---------------- MFMA SAGE transform: out = relu([mean|h] @ WT^T + bl), bf16 ----------------
// Round-9: 1024 thr / 256 rows per block. Same 64KB LDS WT stage serves 2x the rows of the
// verified 512-thr version: 2 blocks/CU = 32 waves/CU (max), WT staging 25->12.5MB.
// Staging re-index only (row=t>>3, seg=t&7, 4 units/thread); swizzle + MFMA phase unchanged.
__global__ __launch_bounds__(1024) void sage_mfma_k(
    const unsigned short* __restrict__ mean,
    const unsigned short* __restrict__ h,
    const unsigned short* __restrict__ WT,   // [128][256] bf16
    const float* __restrict__ bl,
    unsigned short* __restrict__ out, int nN)
{
    __shared__ unsigned short sB[128 * 256];   // exactly 64 KB

    {
        int row = threadIdx.x >> 3, seg = threadIdx.x & 7;
        const short8* srcp = (const short8*)(WT + row * 256 + seg * 32);
        int sw = (row & 7) << 2;
        #pragma unroll
        for (int j = 0; j < 4; ++j) {
            int unit = seg * 4 + j;
            int unit2 = unit ^ sw;
            *(short8*)(sB + row * 256 + unit2 * 8) = srcp[j];
        }
    }
    __syncthreads();

    const int wave = threadIdx.x >> 6;       // 0..15
    const int lane = threadIdx.x & 63;
    const int m = lane & 15;
    const int q = lane >> 4;
    const int row = blockIdx.x * 256 + wave * 16 + m;
    const int rowc = min(row, nN - 1);
    const int swm = (m & 7) << 2;

    f32x4 acc[8] = {};
    #pragma unroll
    for (int ks = 0; ks < 8; ++ks) {
        const unsigned short* Aptr = (ks < 4) ? mean : h;
        short8 a = *(const short8*)(Aptr + (size_t)rowc * HID + (ks & 3) * 32 + q * 8);
        #pragma unroll
        for (int t = 0; t < 8; ++t) {
            int unit2 = (ks * 4 + q) ^ swm;
            short8 b = *(const short8*)(sB + (t * 16 + m) * 256 + unit2 * 8);
            acc[t] = __builtin_amdgcn_mfma_f32_16x16x32_bf16(a, b, acc[t], 0, 0, 0);
        }
    }

    int orow_base = blockIdx.x * 256 + wave * 16 + q * 4;
    #pragma unroll
    for (int t = 0; t < 8; ++t) {
        float bias = bl[t * 16 + m];
        #pragma unroll
        for (int r = 0; r < 4; ++r) {
            int orow = orow_base + r;
            if (orow < nN) {
                float v = fmaxf(acc[t][r] + bias, 0.f);
                out[(size_t)orow * HID + t * 16 + m] = f2bf(v);
            }
        }
    }
}

// ---------------- segmented pool (batch sorted): one block per graph ----------------
__global__ __launch_bounds__(256) void pool_seg_k(const unsigned* __restrict__ h2,
                                                  const int* __restrict__ batch,
                                                  float* __restrict__ pooled, int nN) {
    int g = blockIdx.x;
    int lo = 0, hi = nN;
    while (lo < hi) { int mid = (lo + hi) >> 1; if (batch[mid] < g) lo = mid + 1; else hi = mid; }
    int beg = lo;
    hi = nN;
    while (lo < hi) { int mid = (lo + hi) >> 1; if (batch[mid] <= g) lo = mid + 1; else hi = mid; }
    int end = lo;

    int lane = threadIdx.x & 63;
    int sub  = threadIdx.x >> 6;          // 4 waves
    float s0 = 0.f, s1 = 0.f;
    for (int i = beg + sub; i < end; i += 4) {
        unsigned u = h2[(size_t)i * 64 + lane];
        s0 += __uint_as_float(u << 16);
        s1 += __uint_as_float(u & 0xffff0000u);
    }
    __shared__ float red[4][HID];
    red[sub][2 * lane]     = s0;
    red[sub][2 * lane + 1] = s1;
    __syncthreads();
    if (sub == 0) {
        float v0 = red[0][2 * lane] + red[1][2 * lane] + red[2][2 * lane] + red[3][2 * lane];
        float v1 = red[0][2 * lane + 1] + red[1][2 * lane + 1] + red[2][2 * lane + 1] + red[3][2 * lane + 1];
        pooled[(size_t)g * HID + 2 * lane]     = v0;
        pooled[(size_t)g * HID + 2 * lane + 1] = v1;
    }
}

// ---------------- batchnorm stats: 1024 thr, 8 graph-stripes x 128 features ----------------
__global__ __launch_bounds__(1024) void bn_stats_k(const float* __restrict__ pooled,
                                                   const float* __restrict__ gamma,
                                                   const float* __restrict__ beta,
                                                   float* __restrict__ scale,
                                                   float* __restrict__ shift, int nG) {
    __shared__ float rs[8][HID], rs2[8][HID];
    int j = threadIdx.x & (HID - 1);
    int stripe = threadIdx.x >> 7;         // 0..7
    float s = 0.f, s2 = 0.f;
    for (int g = stripe; g < nG; g += 8) {
        float v = pooled[(size_t)g * HID + j];
        s += v; s2 += v * v;
    }
    rs[stripe][j] = s; rs2[stripe][j] = s2;
    __syncthreads();
    if (threadIdx.x < HID) {
        float S = 0.f, S2 = 0.f;
        #pragma unroll
        for (int k = 0; k < 8; ++k) { S += rs[k][j]; S2 += rs2[k][j]; }
        float invG = 1.0f / (float)nG;
        float mu = S * invG;
        float var = S2 * invG - mu * mu;
        float r = rsqrtf(var + 1e-5f) * gamma[j];
        scale[j] = r;
        shift[j] = beta[j] - mu * r;
    }
}

// ---------------- final FC: one block per graph (round-3 lesson: never collapse to 1 block) ----------------
__global__ __launch_bounds__(LATENT) void fc_k(const float* __restrict__ pooled,
                                               const float* __restrict__ scale,
                                               const float* __restrict__ shift,
                                               const float* __restrict__ fcW,
                                               const float* __restrict__ fcb,
                                               float* __restrict__ out, int nG) {
    int g = blockIdx.x;
    int o = threadIdx.x;
    float acc = fcb[o];
    for (int j = 0; j < HID; ++j) {
        float v = pooled[(size_t)g * HID + j] * scale[j] + shift[j];
        acc += v * fcW[(size_t)j * LATENT + o];
    }
    out[(size_t)g * LATENT + o] = acc;
}

extern "C" void kernel_launch(void* const* d_in, const int* in_sizes, int n_in,
                              void* d_out, int out_size, void* d_ws, size_t ws_size,
                              hipStream_t stream) {
    const float* x     = (const float*)d_in[0];
    const int*   ei    = (const int*)d_in[1];
    const int*   batch = (const int*)d_in[2];
    const float* Wl    = (const float*)d_in[3];
    const float* bl    = (const float*)d_in[4];
    const float* Wr    = (const float*)d_in[5];
    const float* gamma = (const float*)d_in[6];
    const float* beta  = (const float*)d_in[7];
    const float* fcW   = (const float*)d_in[8];
    const float* fcb   = (const float*)d_in[9];
    float* out = (float*)d_out;

    const int nN = in_sizes[0] / HID;      // 50000
    const int nE = in_sizes[1] / 2;        // 800000
    const int nG = out_size / LATENT;      // 256
    const int* src = ei;
    const int* dst = ei + nE;
    const int nbuck = (nN + 127) >> BSHIFT;   // 391
    const int ebB = (nE + EPB - 1) / EPB;     // 782

    unsigned short* hx   = (unsigned short*)d_ws;           // nN*HID bf16
    unsigned short* B1   = hx + (size_t)nN * HID;
    unsigned short* B2   = B1 + (size_t)nN * HID;
    unsigned short* mean = B2 + (size_t)nN * HID;           // aliased by staged (CSR phase only)
    unsigned short* WT   = mean + (size_t)nN * HID;         // 3*128*256 bf16
    float* inv    = (float*)(WT + 3 * 128 * 256);
    float* pooled = inv + nN;
    float* scale  = pooled + (size_t)nG * HID;
    float* shift  = scale + HID;
    int*   row_ptr     = (int*)(shift + HID);               // nN+1
    int*   csr_src     = row_ptr + (nN + 1);
    int*   bucketStart = csr_src + nE;                      // (layout kept)
    int*   bucketTotal = bucketStart + NBUCK_MAX + 1;
    int*   partial     = bucketTotal + NBUCK_MAX;           // ebB*NBUCK_MAX ints
    uint2* staged      = (uint2*)mean;                      // 6.4 MB <= mean's 12.8 MB

    const int n2x = nN * HID / 2;
    const int convx_blocks = (n2x + 255) / 256;

    // ---- CSR build + conversions: 4 launches (coop grid.sync measured ~100us/sync - banned) ----
    stage1_k<<<ebB + 384 + convx_blocks, 256, 0, stream>>>(dst, x, Wl, Wr, partial,
                                                           (unsigned*)hx, WT, row_ptr,
                                                           nE, nbuck, ebB, n2x, nN);
    colscan_k<<<nbuck, 256, 0, stream>>>(partial, bucketTotal, ebB);
    bplace_k<<<ebB, 256, 0, stream>>>(src, dst, partial, bucketTotal, staged, nE, nbuck);
    sort_bucket_k<<<nbuck, 256, 0, stream>>>(staged, bucketTotal, row_ptr, inv, csr_src, nN, nbuck);

    const int gather_blocks = (nN + 3) / 4;
    const int gemm_blocks = (nN + 255) / 256;

    const unsigned short* hcur = hx;
    unsigned short* outs[3] = {B1, B2, B1};
    for (int l = 0; l < 3; ++l) {
        gather_k<<<gather_blocks, 256, 0, stream>>>(row_ptr, csr_src, inv,
                                                    (const uint4*)hcur, (uint4*)mean, nN);
        sage_mfma_k<<<gemm_blocks, 1024, 0, stream>>>(mean, hcur,
                                                      WT + (size_t)l * 128 * 256,
                                                      bl + (size_t)l * HID,
                                                      outs[l], nN);
        hcur = outs[l];
    }

    pool_seg_k<<<nG, 256, 0, stream>>>((const unsigned*)hcur, batch, pooled, nN);
    bn_stats_k<<<1, 1024, 0, stream>>>(pooled, gamma, beta, scale, shift, nG);
    fc_k<<<nG, LATENT, 0, stream>>>(pooled, scale, shift, fcW, fcb, out, nG);
}

// Round 10
// 281.203 us; speedup vs baseline: 1.3535x; 1.0131x over previous
//
#include <hip/hip_runtime.h>
#include <cstdint>
#include <cstddef>

constexpr int HID = 128;
constexpr int LATENT = 64;
constexpr int BSHIFT = 7;           // 128 nodes per bucket
constexpr int NBUCK_MAX = 512;      // supports up to 65536 nodes
constexpr int EPB = 1024;           // edges per block in bucket passes

typedef __attribute__((ext_vector_type(8))) short short8;
typedef __attribute__((ext_vector_type(4))) float f32x4;

__device__ inline unsigned short f2bf(float f) {
    unsigned u = __float_as_uint(f);
    u += 0x7fff + ((u >> 16) & 1);          // RNE
    return (unsigned short)(u >> 16);
}
__device__ inline unsigned pack_bf16x2(float lo, float hi) {
    unsigned ulo = __float_as_uint(lo);
    unsigned uhi = __float_as_uint(hi);
    ulo += 0x7fff + ((ulo >> 16) & 1);
    uhi += 0x7fff + ((uhi >> 16) & 1);
    return (ulo >> 16) | (uhi & 0xffff0000u);
}

// ---- stage 1 (one launch): bucket partial histograms + WT conv + x->bf16 conv ----
__global__ __launch_bounds__(256) void stage1_k(const int* __restrict__ dst,
                                                const float* __restrict__ x,
                                                const float* __restrict__ Wl,
                                                const float* __restrict__ Wr,
                                                int* __restrict__ partial,
                                                unsigned* __restrict__ hx2,
                                                unsigned short* __restrict__ WT,
                                                int* __restrict__ row_ptr,
                                                int nE, int nbuck, int ebB, int n2x, int nN) {
    if (blockIdx.x < (unsigned)ebB) {
        if (blockIdx.x == 0 && threadIdx.x == 0) row_ptr[nN] = nE;
        __shared__ int lh[NBUCK_MAX];
        for (int b = threadIdx.x; b < nbuck; b += 256) lh[b] = 0;
        __syncthreads();
        int base = blockIdx.x * EPB;
        int end = min(base + EPB, nE);
        for (int i = base + threadIdx.x; i < end; i += 256)
            atomicAdd(&lh[dst[i] >> BSHIFT], 1);
        __syncthreads();
        int* row = partial + (size_t)blockIdx.x * NBUCK_MAX;
        for (int b = threadIdx.x; b < nbuck; b += 256) row[b] = lh[b];
    } else if (blockIdx.x < (unsigned)(ebB + 384)) {
        int idx = (blockIdx.x - ebB) * 256 + threadIdx.x;    // < 3*128*256
        int l = idx / (128 * 256);
        int rem = idx % (128 * 256);
        int n = rem / 256;
        int k = rem % 256;
        float v = (k < 128) ? Wl[(size_t)l * 16384 + (size_t)k * 128 + n]
                            : Wr[(size_t)l * 16384 + (size_t)(k - 128) * 128 + n];
        WT[idx] = f2bf(v);
    } else {
        int i = (blockIdx.x - ebB - 384) * 256 + threadIdx.x;
        if (i < n2x) {
            float2 v = ((const float2*)x)[i];
            hx2[i] = pack_bf16x2(v.x, v.y);
        }
    }
}

// ---- stage 2: per-bucket column scan over block partials (one block per bucket) ----
__global__ __launch_bounds__(256) void colscan_k(int* __restrict__ partial,
                                                 int* __restrict__ bucketTotal, int ebB) {
    int b = blockIdx.x;
    int t = threadIdx.x;
    const int CH = (ebB + 255) / 256;     // <= 8 for ebB <= 2048
    int vals[8];
    int s = 0;
    #pragma unroll
    for (int c = 0; c < 8; ++c) {
        if (c >= CH) break;
        int k = t * CH + c;
        int v = (k < ebB) ? partial[(size_t)k * NBUCK_MAX + b] : 0;
        vals[c] = v; s += v;
    }
    __shared__ int part[256];
    part[t] = s;
    __syncthreads();
    for (int d = 1; d < 256; d <<= 1) {
        int u = (t >= d) ? part[t - d] : 0;
        __syncthreads();
        if (t >= d) part[t] += u;
        __syncthreads();
    }
    int run = (t == 0) ? 0 : part[t - 1];
    #pragma unroll
    for (int c = 0; c < 8; ++c) {
        if (c >= CH) break;
        int k = t * CH + c;
        if (k < ebB) partial[(size_t)k * NBUCK_MAX + b] = run;
        run += vals[c];
    }
    if (t == 255) bucketTotal[b] = run;
}

// ---- stage 3: bucket placement; packed 32-bit staged entries (src<<7 | dst&127) ----
__global__ __launch_bounds__(256) void bplace_k(const int* __restrict__ src,
                                                const int* __restrict__ dst,
                                                const int* __restrict__ partial,
                                                const int* __restrict__ bucketTotal,
                                                unsigned* __restrict__ staged, int nE, int nbuck) {
    __shared__ int lh[NBUCK_MAX];
    __shared__ int lb[NBUCK_MAX];
    __shared__ int part[256];
    int t = threadIdx.x;
    for (int b = t; b < nbuck; b += 256) lh[b] = 0;
    int v0 = (2 * t < nbuck) ? bucketTotal[2 * t] : 0;
    int v1 = (2 * t + 1 < nbuck) ? bucketTotal[2 * t + 1] : 0;
    part[t] = v0 + v1;
    __syncthreads();
    for (int d = 1; d < 256; d <<= 1) {
        int u = (t >= d) ? part[t - d] : 0;
        __syncthreads();
        if (t >= d) part[t] += u;
        __syncthreads();
    }
    const int* myPre = partial + (size_t)blockIdx.x * NBUCK_MAX;
    int excl = part[t] - v0 - v1;       // exclusive prefix of pair t
    if (2 * t < nbuck)     lb[2 * t]     = excl + myPre[2 * t];
    if (2 * t + 1 < nbuck) lb[2 * t + 1] = excl + v0 + myPre[2 * t + 1];
    __syncthreads();
    int base = blockIdx.x * EPB;
    int end = min(base + EPB, nE);
    for (int i = base + t; i < end; i += 256) {
        int d = dst[i];
        int b = d >> BSHIFT;
        int loc = atomicAdd(&lh[b], 1);      // LDS-only cursor
        staged[lb[b] + loc] = ((unsigned)src[i] << 7) | (unsigned)(d & 127);
    }
}

// ---- stage 4: per-bucket finish: counts -> row_ptr/inv, place csr_src (L2-local) ----
__global__ __launch_bounds__(256) void sort_bucket_k(const unsigned* __restrict__ staged,
                                                     const int* __restrict__ bucketTotal,
                                                     int* __restrict__ row_ptr,
                                                     float* __restrict__ inv,
                                                     int* __restrict__ csr_src, int nN, int nbuck) {
    __shared__ int part[256];
    __shared__ int cnt[128];
    __shared__ int rp[128];
    __shared__ int sBeg;
    int g = blockIdx.x;
    int t = threadIdx.x;
    int v0 = (2 * t < nbuck) ? bucketTotal[2 * t] : 0;
    int v1 = (2 * t + 1 < nbuck) ? bucketTotal[2 * t + 1] : 0;
    part[t] = v0 + v1;
    __syncthreads();
    for (int d = 1; d < 256; d <<= 1) {
        int u = (t >= d) ? part[t - d] : 0;
        __syncthreads();
        if (t >= d) part[t] += u;
        __syncthreads();
    }
    if (t == (g >> 1)) {
        int excl = part[t] - v0 - v1;
        sBeg = (g & 1) ? (excl + v0) : excl;
    }
    if (t < 128) cnt[t] = 0;
    __syncthreads();
    int beg = sBeg;
    int end = beg + bucketTotal[g];
    for (int i = beg + t; i < end; i += 256)
        atomicAdd(&cnt[staged[i] & 127], 1);
    __syncthreads();
    if (t < 128) rp[t] = cnt[t];
    __syncthreads();
    #pragma unroll
    for (int d = 1; d < 128; d <<= 1) {
        int v = 0;
        if (t < 128 && t >= d) v = rp[t - d];
        __syncthreads();
        if (t < 128 && t >= d) rp[t] += v;
        __syncthreads();
    }
    if (t < 128) {
        int c = cnt[t];
        int excl = rp[t] - c;
        int node = (g << BSHIFT) + t;
        if (node < nN) {
            row_ptr[node] = beg + excl;
            inv[node] = 1.0f / fmaxf((float)c, 1.0f);
        }
        cnt[t] = excl;               // reuse as cursor
    }
    __syncthreads();
    for (int i = beg + t; i < end; i += 256) {
        unsigned e = staged[i];
        int pos = atomicAdd(&cnt[e & 127], 1);
        csr_src[beg + pos] = (int)(e >> 7);
    }
}

// ---------------- pull-gather mean: uint4 loads, 16 lanes/row, 4-deep ILP ----------------
// 256 thr = 4 waves, ONE NODE PER WAVE. ROUND-7 VERIFIED VERSION.
// Gather runs at ~6.0 TB/s = 95% of the 6.29 TB/s streaming ceiling on random 256B rows.
// Round-8 A/B: locality passes regress 1.8x (issue-bound). This kernel is CLOSED.
__global__ __launch_bounds__(256) void gather_k(const int* __restrict__ row_ptr,
                                                const int* __restrict__ csr_src,
                                                const float* __restrict__ inv,
                                                const uint4* __restrict__ h4,
                                                uint4* __restrict__ mean4, int nN) {
    int w = blockIdx.x * 4 + (threadIdx.x >> 6);
    if (w >= nN) return;
    int lane = threadIdx.x & 63;
    int quarter = lane >> 4;
    int col = lane & 15;
    int beg = row_ptr[w], end = row_ptr[w + 1];
    float accA[8] = {}, accB[8] = {}, accC[8] = {}, accD[8] = {};
    for (int base = beg; base < end; base += 64) {
        int navail = min(64, end - base);
        int idx = (lane < navail) ? csr_src[base + lane] : 0;
        for (int j = 0; j < navail; j += 16) {
            int e0 = j + quarter;
            int e1 = j + 4 + quarter;
            int e2 = j + 8 + quarter;
            int e3 = j + 12 + quarter;
            int s0 = __shfl(idx, e0, 64);
            int s1 = __shfl(idx, e1, 64);
            int s2 = __shfl(idx, e2, 64);
            int s3 = __shfl(idx, e3, 64);
            uint4 u0 = make_uint4(0u, 0u, 0u, 0u);
            uint4 u1 = make_uint4(0u, 0u, 0u, 0u);
            uint4 u2 = make_uint4(0u, 0u, 0u, 0u);
            uint4 u3 = make_uint4(0u, 0u, 0u, 0u);
            if (e0 < navail) u0 = h4[(size_t)s0 * 16 + col];
            if (e1 < navail) u1 = h4[(size_t)s1 * 16 + col];
            if (e2 < navail) u2 = h4[(size_t)s2 * 16 + col];
            if (e3 < navail) u3 = h4[(size_t)s3 * 16 + col];
            if (e0 < navail) {
                accA[0] += __uint_as_float(u0.x << 16); accA[1] += __uint_as_float(u0.x & 0xffff0000u);
                accA[2] += __uint_as_float(u0.y << 16); accA[3] += __uint_as_float(u0.y & 0xffff0000u);
                accA[4] += __uint_as_float(u0.z << 16); accA[5] += __uint_as_float(u0.z & 0xffff0000u);
                accA[6] += __uint_as_float(u0.w << 16); accA[7] += __uint_as_float(u0.w & 0xffff0000u);
            }
            if (e1 < navail) {
                accB[0] += __uint_as_float(u1.x << 16); accB[1] += __uint_as_float(u1.x & 0xffff0000u);
                accB[2] += __uint_as_float(u1.y << 16); accB[3] += __uint_as_float(u1.y & 0xffff0000u);
                accB[4] += __uint_as_float(u1.z << 16); accB[5] += __uint_as_float(u1.z & 0xffff0000u);
                accB[6] += __uint_as_float(u1.w << 16); accB[7] += __uint_as_float(u1.w & 0xffff0000u);
            }
            if (e2 < navail) {
                accC[0] += __uint_as_float(u2.x << 16); accC[1] += __uint_as_float(u2.x & 0xffff0000u);
                accC[2] += __uint_as_float(u2.y << 16); accC[3] += __uint_as_float(u2.y & 0xffff0000u);
                accC[4] += __uint_as_float(u2.z << 16); accC[5] += __uint_as_float(u2.z & 0xffff0000u);
                accC[6] += __uint_as_float(u2.w << 16); accC[7] += __uint_as_float(u2.w & 0xffff0000u);
            }
            if (e3 < navail) {
                accD[0] += __uint_as_float(u3.x << 16); accD[1] += __uint_as_float(u3.x & 0xffff0000u);
                accD[2] += __uint_as_float(u3.y << 16); accD[3] += __uint_as_float(u3.y & 0xffff0000u);
                accD[4] += __uint_as_float(u3.z << 16); accD[5] += __uint_as_float(u3.z & 0xffff0000u);
                accD[6] += __uint_as_float(u3.w << 16); accD[7] += __uint_as_float(u3.w & 0xffff0000u);
            }
        }
    }
    #pragma unroll
    for (int k = 0; k < 8; ++k) {
        float v = (accA[k] + accB[k]) + (accC[k] + accD[k]);
        v += __shfl_xor(v, 16, 64);
        v += __shfl_xor(v, 32, 64);
        accA[k] = v;
    }
    if (quarter == 0) {
        float iv = inv[w];
        uint4 o;
        o.x = pack_bf16x2(accA[0] * iv, accA[1] * iv);
        o.y = pack_bf16x2(accA[2] * iv, accA[3] * iv);
        o.z = pack_bf16x2(accA[4] * iv, accA[5] * iv);
        o.w = pack_bf16x2(accA[6] * iv, accA[7] * iv);
        mean4[(size_t)w * 16 + col] = o;
    }
}

// ---------------- MFMA SAGE transform: out = relu([mean|h] @ WT^T + bl), bf16 ----------------
// 1024 thr / 256 rows per block (verified round 9): 64KB LDS serves 2 blocks/CU = 32 waves/CU.
__global__ __launch_bounds__(1024) void sage_mfma_k(
    const unsigned short* __restrict__ mean,
    const unsigned short* __restrict__ h,
    const unsigned short* __restrict__ WT,   // [128][256] bf16
    const float* __restrict__ bl,
    unsigned short* __restrict__ out, int nN)
{
    __shared__ unsigned short sB[128 * 256];   // exactly 64 KB

    {
        int row = threadIdx.x >> 3, seg = threadIdx.x & 7;
        const short8* srcp = (const short8*)(WT + row * 256 + seg * 32);
        int sw = (row & 7) << 2;
        #pragma unroll
        for (int j = 0; j < 4; ++j) {
            int unit = seg * 4 + j;
            int unit2 = unit ^ sw;
            *(short8*)(sB + row * 256 + unit2 * 8) = srcp[j];
        }
    }
    __syncthreads();

    const int wave = threadIdx.x >> 6;       // 0..15
    const int lane = threadIdx.x & 63;
    const int m = lane & 15;
    const int q = lane >> 4;
    const int row = blockIdx.x * 256 + wave * 16 + m;
    const int rowc = min(row, nN - 1);
    const int swm = (m & 7) << 2;

    f32x4 acc[8] = {};
    #pragma unroll
    for (int ks = 0; ks < 8; ++ks) {
        const unsigned short* Aptr = (ks < 4) ? mean : h;
        short8 a = *(const short8*)(Aptr + (size_t)rowc * HID + (ks & 3) * 32 + q * 8);
        #pragma unroll
        for (int t = 0; t < 8; ++t) {
            int unit2 = (ks * 4 + q) ^ swm;
            short8 b = *(const short8*)(sB + (t * 16 + m) * 256 + unit2 * 8);
            acc[t] = __builtin_amdgcn_mfma_f32_16x16x32_bf16(a, b, acc[t], 0, 0, 0);
        }
    }

    int orow_base = blockIdx.x * 256 + wave * 16 + q * 4;
    #pragma unroll
    for (int t = 0; t < 8; ++t) {
        float bias = bl[t * 16 + m];
        #pragma unroll
        for (int r = 0; r < 4; ++r) {
            int orow = orow_base + r;
            if (orow < nN) {
                float v = fmaxf(acc[t][r] + bias, 0.f);
                out[(size_t)orow * HID + t * 16 + m] = f2bf(v);
            }
        }
    }
}

// ---------------- segmented pool (batch sorted): one block per graph ----------------
__global__ __launch_bounds__(256) void pool_seg_k(const unsigned* __restrict__ h2,
                                                  const int* __restrict__ batch,
                                                  float* __restrict__ pooled, int nN) {
    int g = blockIdx.x;
    int lo = 0, hi = nN;
    while (lo < hi) { int mid = (lo + hi) >> 1; if (batch[mid] < g) lo = mid + 1; else hi = mid; }
    int beg = lo;
    hi = nN;
    while (lo < hi) { int mid = (lo + hi) >> 1; if (batch[mid] <= g) lo = mid + 1; else hi = mid; }
    int end = lo;

    int lane = threadIdx.x & 63;
    int sub  = threadIdx.x >> 6;          // 4 waves
    float s0 = 0.f, s1 = 0.f;
    for (int i = beg + sub; i < end; i += 4) {
        unsigned u = h2[(size_t)i * 64 + lane];
        s0 += __uint_as_float(u << 16);
        s1 += __uint_as_float(u & 0xffff0000u);
    }
    __shared__ float red[4][HID];
    red[sub][2 * lane]     = s0;
    red[sub][2 * lane + 1] = s1;
    __syncthreads();
    if (sub == 0) {
        float v0 = red[0][2 * lane] + red[1][2 * lane] + red[2][2 * lane] + red[3][2 * lane];
        float v1 = red[0][2 * lane + 1] + red[1][2 * lane + 1] + red[2][2 * lane + 1] + red[3][2 * lane + 1];
        pooled[(size_t)g * HID + 2 * lane]     = v0;
        pooled[(size_t)g * HID + 2 * lane + 1] = v1;
    }
}

// ---------------- fused BN + FC: 256 blocks x 128 thr; stats redundant per block ----------------
// pooled (128 KB) is L2-hot; 256 blocks x 128 KB = 33 MB aggregate L2 reads ~1 us.
// FC stays one block per graph (round-3 lesson: never collapse FC onto one block).
__global__ __launch_bounds__(128) void fcbn_k(const float* __restrict__ pooled,
                                              const float* __restrict__ gamma,
                                              const float* __restrict__ beta,
                                              const float* __restrict__ fcW,
                                              const float* __restrict__ fcb,
                                              float* __restrict__ out, int nG) {
    __shared__ float scale_s[HID], shift_s[HID];
    __shared__ float fr[2][LATENT];
    int g = blockIdx.x;
    int j = threadIdx.x;                  // 0..127, one feature per thread
    float s = 0.f, s2 = 0.f;
    #pragma unroll 8
    for (int gg = 0; gg < nG; ++gg) {
        float v = pooled[(size_t)gg * HID + j];
        s += v; s2 += v * v;
    }
    float invG = 1.0f / (float)nG;
    float mu = s * invG;
    float var = s2 * invG - mu * mu;
    float r = rsqrtf(var + 1e-5f) * gamma[j];
    scale_s[j] = r;
    shift_s[j] = beta[j] - mu * r;
    __syncthreads();
    int o = j & 63;
    int half = j >> 6;
    float acc = 0.f;
    #pragma unroll 8
    for (int jj = half * 64; jj < half * 64 + 64; ++jj) {
        float v = pooled[(size_t)g * HID + jj] * scale_s[jj] + shift_s[jj];
        acc += v * fcW[(size_t)jj * LATENT + o];
    }
    fr[half][o] = acc;
    __syncthreads();
    if (j < LATENT)
        out[(size_t)g * LATENT + j] = fcb[j] + fr[0][j] + fr[1][j];
}

extern "C" void kernel_launch(void* const* d_in, const int* in_sizes, int n_in,
                              void* d_out, int out_size, void* d_ws, size_t ws_size,
                              hipStream_t stream) {
    const float* x     = (const float*)d_in[0];
    const int*   ei    = (const int*)d_in[1];
    const int*   batch = (const int*)d_in[2];
    const float* Wl    = (const float*)d_in[3];
    const float* bl    = (const float*)d_in[4];
    const float* Wr    = (const float*)d_in[5];
    const float* gamma = (const float*)d_in[6];
    const float* beta  = (const float*)d_in[7];
    const float* fcW   = (const float*)d_in[8];
    const float* fcb   = (const float*)d_in[9];
    float* out = (float*)d_out;

    const int nN = in_sizes[0] / HID;      // 50000
    const int nE = in_sizes[1] / 2;        // 800000
    const int nG = out_size / LATENT;      // 256
    const int* src = ei;
    const int* dst = ei + nE;
    const int nbuck = (nN + 127) >> BSHIFT;   // 391
    const int ebB = (nE + EPB - 1) / EPB;     // 782

    unsigned short* hx   = (unsigned short*)d_ws;           // nN*HID bf16
    unsigned short* B1   = hx + (size_t)nN * HID;
    unsigned short* B2   = B1 + (size_t)nN * HID;
    unsigned short* mean = B2 + (size_t)nN * HID;           // aliased by staged (CSR phase only)
    unsigned short* WT   = mean + (size_t)nN * HID;         // 3*128*256 bf16
    float* inv    = (float*)(WT + 3 * 128 * 256);
    float* pooled = inv + nN;
    float* scale  = pooled + (size_t)nG * HID;
    float* shift  = scale + HID;
    int*   row_ptr     = (int*)(shift + HID);               // nN+1
    int*   csr_src     = row_ptr + (nN + 1);
    int*   bucketStart = csr_src + nE;                      // (layout kept)
    int*   bucketTotal = bucketStart + NBUCK_MAX + 1;
    int*   partial     = bucketTotal + NBUCK_MAX;           // ebB*NBUCK_MAX ints
    unsigned* staged   = (unsigned*)mean;                   // 3.2 MB <= mean's 12.8 MB
    (void)scale; (void)shift;

    const int n2x = nN * HID / 2;
    const int convx_blocks = (n2x + 255) / 256;

    // ---- CSR build + conversions: 4 launches (coop grid.sync measured ~100us/sync - banned) ----
    stage1_k<<<ebB + 384 + convx_blocks, 256, 0, stream>>>(dst, x, Wl, Wr, partial,
                                                           (unsigned*)hx, WT, row_ptr,
                                                           nE, nbuck, ebB, n2x, nN);
    colscan_k<<<nbuck, 256, 0, stream>>>(partial, bucketTotal, ebB);
    bplace_k<<<ebB, 256, 0, stream>>>(src, dst, partial, bucketTotal, staged, nE, nbuck);
    sort_bucket_k<<<nbuck, 256, 0, stream>>>(staged, bucketTotal, row_ptr, inv, csr_src, nN, nbuck);

    const int gather_blocks = (nN + 3) / 4;
    const int gemm_blocks = (nN + 255) / 256;

    const unsigned short* hcur = hx;
    unsigned short* outs[3] = {B1, B2, B1};
    for (int l = 0; l < 3; ++l) {
        gather_k<<<gather_blocks, 256, 0, stream>>>(row_ptr, csr_src, inv,
                                                    (const uint4*)hcur, (uint4*)mean, nN);
        sage_mfma_k<<<gemm_blocks, 1024, 0, stream>>>(mean, hcur,
                                                      WT + (size_t)l * 128 * 256,
                                                      bl + (size_t)l * HID,
                                                      outs[l], nN);
        hcur = outs[l];
    }

    pool_seg_k<<<nG, 256, 0, stream>>>((const unsigned*)hcur, batch, pooled, nN);
    fcbn_k<<<nG, 128, 0, stream>>>(pooled, gamma, beta, fcW, fcb, out, nG);
}